// Round 9
// baseline (195.119 us; speedup 1.0000x reference)
//
#include <hip/hip_runtime.h>

#define EPB 8           // envs per block
#define BLOCK 64        // ONE wave: every env (8 lanes) is wave-internal
#define HS 292          // H LDS stride (288 + 4)
#define GS 148          // G/Ginv LDS stride (144 + 4)
#define SS 28           // b / aux stride (24 + 4)

#define WFENCE() __builtin_amdgcn_wave_barrier()   // compiler fence, 0 instr

// acc += dot(f4, s4)
#define FMA4(acc, f, s)                                         \
  acc = fmaf((f).x, (s).x,                                      \
        fmaf((f).y, (s).y,                                      \
        fmaf((f).z, (s).z,                                      \
        fmaf((f).w, (s).w, (acc)))))

// acc4 += s * v4
#define VFMA(acc, s, v)                                         \
  { (acc).x = fmaf((s), (v).x, (acc).x);                        \
    (acc).y = fmaf((s), (v).y, (acc).y);                        \
    (acc).z = fmaf((s), (v).z, (acc).z);                        \
    (acc).w = fmaf((s), (v).w, (acc).w); }

struct Row6 { float4 c0, c1, c2, c3, c4, c5; };

template<int J>
__device__ __forceinline__ float relem(const Row6& R) {
  if constexpr (J / 4 == 0) { if constexpr (J % 4 == 0) return R.c0.x; else if constexpr (J % 4 == 1) return R.c0.y; else if constexpr (J % 4 == 2) return R.c0.z; else return R.c0.w; }
  else if constexpr (J / 4 == 1) { if constexpr (J % 4 == 0) return R.c1.x; else if constexpr (J % 4 == 1) return R.c1.y; else if constexpr (J % 4 == 2) return R.c1.z; else return R.c1.w; }
  else if constexpr (J / 4 == 2) { if constexpr (J % 4 == 0) return R.c2.x; else if constexpr (J % 4 == 1) return R.c2.y; else if constexpr (J % 4 == 2) return R.c2.z; else return R.c2.w; }
  else if constexpr (J / 4 == 3) { if constexpr (J % 4 == 0) return R.c3.x; else if constexpr (J % 4 == 1) return R.c3.y; else if constexpr (J % 4 == 2) return R.c3.z; else return R.c3.w; }
  else if constexpr (J / 4 == 4) { if constexpr (J % 4 == 0) return R.c4.x; else if constexpr (J % 4 == 1) return R.c4.y; else if constexpr (J % 4 == 2) return R.c4.z; else return R.c4.w; }
  else                            { if constexpr (J % 4 == 0) return R.c5.x; else if constexpr (J % 4 == 1) return R.c5.y; else if constexpr (J % 4 == 2) return R.c5.z; else return R.c5.w; }
}

// register crossbar: value of v in lane (pbase>>2)+ (off>>2)
__device__ __forceinline__ float lanebc(int pbase, int off, float v) {
  return __int_as_float(__builtin_amdgcn_ds_bpermute(pbase + off, __float_as_int(v)));
}

template<int K>
__device__ __forceinline__ float getel(const float4& a, const float4& b, const float4& c) {
  if constexpr (K == 0) return a.x; else if constexpr (K == 1) return a.y;
  else if constexpr (K == 2) return a.z; else if constexpr (K == 3) return a.w;
  else if constexpr (K == 4) return b.x; else if constexpr (K == 5) return b.y;
  else if constexpr (K == 6) return b.z; else if constexpr (K == 7) return b.w;
  else if constexpr (K == 8) return c.x; else if constexpr (K == 9) return c.y;
  else if constexpr (K == 10) return c.z; else return c.w;
}
template<int K>
__device__ __forceinline__ void setel(float4& a, float4& b, float4& c, float v) {
  if constexpr (K == 0) a.x = v; else if constexpr (K == 1) a.y = v;
  else if constexpr (K == 2) a.z = v; else if constexpr (K == 3) a.w = v;
  else if constexpr (K == 4) b.x = v; else if constexpr (K == 5) b.y = v;
  else if constexpr (K == 6) b.z = v; else if constexpr (K == 7) b.w = v;
  else if constexpr (K == 8) c.x = v; else if constexpr (K == 9) c.y = v;
  else if constexpr (K == 10) c.z = v; else c.w = v;
}

// In-place Gauss-Jordan inversion step in LDS (SPD, no pivoting). Wave-internal.
template<int K>
__device__ __forceinline__ void gj_step(float* A, int t) {
  if (t == K || t + 8 == K) {
    float4* r = (float4*)(A + K * 12);
    float4 a = r[0], b = r[1], c = r[2];
    float ip = 1.0f / getel<K>(a, b, c);
    setel<K>(a, b, c, 1.0f);
    a.x *= ip; a.y *= ip; a.z *= ip; a.w *= ip;
    b.x *= ip; b.y *= ip; b.z *= ip; b.w *= ip;
    c.x *= ip; c.y *= ip; c.z *= ip; c.w *= ip;
    r[0] = a; r[1] = b; r[2] = c;
  }
  WFENCE();
  const float4* pr = (const float4*)(A + K * 12);
  float4 p0 = pr[0], p1 = pr[1], p2 = pr[2];
  {
    float4* rr = (float4*)(A + t * 12);
    float4 a = rr[0], b = rr[1], c = rr[2];
    float f = getel<K>(a, b, c);
    if (t == K) f = 0.0f; else setel<K>(a, b, c, 0.0f);
    a.x = fmaf(-f, p0.x, a.x); a.y = fmaf(-f, p0.y, a.y);
    a.z = fmaf(-f, p0.z, a.z); a.w = fmaf(-f, p0.w, a.w);
    b.x = fmaf(-f, p1.x, b.x); b.y = fmaf(-f, p1.y, b.y);
    b.z = fmaf(-f, p1.z, b.z); b.w = fmaf(-f, p1.w, b.w);
    c.x = fmaf(-f, p2.x, c.x); c.y = fmaf(-f, p2.y, c.y);
    c.z = fmaf(-f, p2.z, c.z); c.w = fmaf(-f, p2.w, c.w);
    rr[0] = a; rr[1] = b; rr[2] = c;
  }
  if (t < 4) {
    const int i = t + 8;
    float4* rr = (float4*)(A + i * 12);
    float4 a = rr[0], b = rr[1], c = rr[2];
    float f = getel<K>(a, b, c);
    if (i == K) f = 0.0f; else setel<K>(a, b, c, 0.0f);
    a.x = fmaf(-f, p0.x, a.x); a.y = fmaf(-f, p0.y, a.y);
    a.z = fmaf(-f, p0.z, a.z); a.w = fmaf(-f, p0.w, a.w);
    b.x = fmaf(-f, p1.x, b.x); b.y = fmaf(-f, p1.y, b.y);
    b.z = fmaf(-f, p1.z, b.z); b.w = fmaf(-f, p1.w, b.w);
    c.x = fmaf(-f, p2.x, c.x); c.y = fmaf(-f, p2.y, c.y);
    c.z = fmaf(-f, p2.z, c.z); c.w = fmaf(-f, p2.w, c.w);
    rr[0] = a; rr[1] = b; rr[2] = c;
  }
  WFENCE();
}
template<int K>
__device__ __forceinline__ void gj_all(float* A, int t) {
  gj_step<K>(A, t);
  if constexpr (K < 11) gj_all<K + 1>(A, t);
}

__device__ __forceinline__ float dot12(float4 a0, float4 a1, float4 a2,
                                       const float* p) {
  const float4* p4 = (const float4*)p;
  float4 b0 = p4[0], b1 = p4[1], b2 = p4[2];
  float acc = 0.f;
  FMA4(acc, a0, b0); FMA4(acc, a1, b1); FMA4(acc, a2, b2);
  return acc;
}

__device__ __forceinline__ void build_gram_row(const float* myH, float* gi,
                                               int i, bool addP) {
  float4 a0 = {0,0,0,0}, a1 = {0,0,0,0}, a2 = {0,0,0,0};
#pragma unroll
  for (int k = 0; k < 24; ++k) {
    float coef = myH[k * 12 + i];
    const float4* hk = (const float4*)(myH + k * 12);
    float4 h0 = hk[0], h1 = hk[1], h2 = hk[2];
    VFMA(a0, coef, h0); VFMA(a1, coef, h1); VFMA(a2, coef, h2);
  }
  float4* g = (float4*)(gi + i * 12);
  if (addP) {
    float4 q0 = g[0], q1 = g[1], q2 = g[2];
    a0.x += q0.x; a0.y += q0.y; a0.z += q0.z; a0.w += q0.w;
    a1.x += q1.x; a1.y += q1.y; a1.z += q1.z; a1.w += q1.w;
    a2.x += q2.x; a2.y += q2.y; a2.z += q2.z; a2.w += q2.w;
  }
  g[0] = a0; g[1] = a1; g[2] = a2;
}

__device__ __forceinline__ Row6 build_row(const float* myH, const float* gi, int r) {
  const float4* hr4 = (const float4*)(myH + r * 12);
  float4 h0 = hr4[0], h1 = hr4[1], h2 = hr4[2];
  float4 gA = {0,0,0,0}, gB = {0,0,0,0}, gC = {0,0,0,0};
#define ACC_G(c, coef)                                          \
  { const float4* g4 = (const float4*)(gi + (c) * 12);          \
    float4 r0 = g4[0], r1 = g4[1], r2 = g4[2];                  \
    VFMA(gA, coef, r0); VFMA(gB, coef, r1); VFMA(gC, coef, r2); }
  ACC_G(0, h0.x) ACC_G(1, h0.y) ACC_G(2,  h0.z) ACC_G(3,  h0.w)
  ACC_G(4, h1.x) ACC_G(5, h1.y) ACC_G(6,  h1.z) ACC_G(7,  h1.w)
  ACC_G(8, h2.x) ACC_G(9, h2.y) ACC_G(10, h2.z) ACC_G(11, h2.w)
#undef ACC_G
  Row6 R;
#define FEL(j) ((((j) == r) ? 1.0f : 0.0f) - dot12(gA, gB, gC, myH + (j) * 12))
  R.c0 = make_float4(FEL(0),  FEL(1),  FEL(2),  FEL(3));
  R.c1 = make_float4(FEL(4),  FEL(5),  FEL(6),  FEL(7));
  R.c2 = make_float4(FEL(8),  FEL(9),  FEL(10), FEL(11));
  R.c3 = make_float4(FEL(12), FEL(13), FEL(14), FEL(15));
  R.c4 = make_float4(FEL(16), FEL(17), FEL(18), FEL(19));
  R.c5 = make_float4(FEL(20), FEL(21), FEL(22), FEL(23));
#undef FEL
  return R;
}

__global__ __launch_bounds__(BLOCK)
void pdhg_kernel(const float* __restrict__ P, const float* __restrict__ q,
                 const float* __restrict__ H, const float* __restrict__ b,
                 const float* __restrict__ cf, const int* __restrict__ itp,
                 float* __restrict__ out, int Btot) {
  __shared__ __align__(16) float sH[EPB * HS];
  __shared__ __align__(16) float sGi[EPB * GS];   // P -> G -> Ginv -> HtH -> inv
  __shared__ __align__(16) float sB[EPB * SS];    // b (setup only)
  __shared__ __align__(16) float sAux[EPB * SS];  // q|y, later z-b

  const int tid = threadIdx.x;                    // 0..63, one wave
  const int e   = tid >> 3;
  const int t   = tid & 7;
  const int env = blockIdx.x * EPB + e;
  const int niter = itp[0];
  const int r0w = 3 * t;
  const int pbase = (tid & 56) << 2;              // env-base lane * 4 for bpermute

  // ---- per-wave float4 staging: H, P, q, b ----
  {
    const float4* gH = (const float4*)(H + (size_t)blockIdx.x * EPB * 288);
#pragma unroll
    for (int rep = 0; rep < 9; ++rep) {           // 8*72 = 576 float4
      int i = tid + rep * 64;
      int ee = i / 72, off = i - ee * 72;
      *(float4*)&sH[ee * HS + off * 4] = gH[i];
    }
    const float4* gP = (const float4*)(P + (size_t)blockIdx.x * EPB * 144);
#pragma unroll
    for (int rep = 0; rep < 4; ++rep) {           // 8*36 = 288 float4
      int i = tid + rep * 64;
      int ee = i / 36, off = i - ee * 36;
      *(float4*)&sGi[ee * GS + off * 4] = gP[i];
    }
    { int i = tid + 256; if (tid < 32) {
        int ee = i / 36, off = i - ee * 36;
        *(float4*)&sGi[ee * GS + off * 4] = gP[i]; } }
    const float4* gq = (const float4*)(q + (size_t)blockIdx.x * EPB * 12);
    if (tid < EPB * 3) {
      int ee = tid / 3, off = tid - ee * 3;
      *(float4*)&sAux[ee * SS + off * 4] = gq[tid];
    }
    const float4* gb = (const float4*)(b + (size_t)blockIdx.x * EPB * 24);
    if (tid < EPB * 6) {
      int ee = tid / 6, off = tid - ee * 6;
      *(float4*)&sB[ee * SS + off * 4] = gb[tid];
    }
  }
  WFENCE();

  const float* myH = &sH[e * HS];
  float* giB = &sGi[e * GS];
  float* auxB = &sAux[e * SS];
  const float* bB = &sB[e * SS];

  // ---- G = P + HtH; invert in place (wave-internal, no barriers) ----
  build_gram_row(myH, giB, t, true);
  if (t < 4) build_gram_row(myH, giB, t + 8, true);
  WFENCE();
  gj_all<0>(giB, t);

  // ---- y = Ginv * q ----
  {
    const float4* gr = (const float4*)(giB + t * 12);
    auxB[12 + t] = dot12(gr[0], gr[1], gr[2], auxB);
    if (t < 4) {
      const float4* gr8 = (const float4*)(giB + (t + 8) * 12);
      auxB[12 + t + 8] = dot12(gr8[0], gr8[1], gr8[2], auxB);
    }
  }
  WFENCE();

  // ---- Fm rows (named float4s), mu = H*y - Fm*b ----
  Row6 F0 = build_row(myH, giB, r0w + 0);
  Row6 F1 = build_row(myH, giB, r0w + 1);
  Row6 F2 = build_row(myH, giB, r0w + 2);
  float mu0, mu1, mu2;
  {
    const float4* h0 = (const float4*)(myH + (r0w + 0) * 12);
    const float4* h1 = (const float4*)(myH + (r0w + 1) * 12);
    const float4* h2 = (const float4*)(myH + (r0w + 2) * 12);
    const float* y = auxB + 12;
    float u0 = dot12(h0[0], h0[1], h0[2], y);
    float u1 = dot12(h1[0], h1[1], h1[2], y);
    float u2 = dot12(h2[0], h2[1], h2[2], y);
    const float4* bv = (const float4*)bB;
    float d0 = 0.f, d1 = 0.f, d2 = 0.f;
    float4 v;
    v = bv[0]; FMA4(d0, F0.c0, v); FMA4(d1, F1.c0, v); FMA4(d2, F2.c0, v);
    v = bv[1]; FMA4(d0, F0.c1, v); FMA4(d1, F1.c1, v); FMA4(d2, F2.c1, v);
    v = bv[2]; FMA4(d0, F0.c2, v); FMA4(d1, F1.c2, v); FMA4(d2, F2.c2, v);
    v = bv[3]; FMA4(d0, F0.c3, v); FMA4(d1, F1.c3, v); FMA4(d2, F2.c3, v);
    v = bv[4]; FMA4(d0, F0.c4, v); FMA4(d1, F1.c4, v); FMA4(d2, F2.c4, v);
    v = bv[5]; FMA4(d0, F0.c5, v); FMA4(d1, F1.c5, v); FMA4(d2, F2.c5, v);
    mu0 = u0 - d0;
    mu1 = u1 - d1;
    mu2 = u2 - d2;
  }
  float cfr0 = cf[(size_t)env * 24 + r0w];
  float cfr1 = cf[(size_t)env * 24 + r0w + 1];
  float cfr2 = cf[(size_t)env * 24 + r0w + 2];

  // ---- iterations: NO LDS memory — s exchanged via ds_bpermute crossbar ----
  float l0 = 0.f, l1 = 0.f, l2 = 0.f, z0 = 0.f, z1 = 0.f, z2 = 0.f;
  for (int it = 0; it < niter; ++it) {
    float s0 = l0 + z0, s1 = l1 + z1, s2 = l2 + z2;
    // two accumulator chains per row (halve FMA dep depth)
    float wA0 = mu0, wA1 = mu1, wA2 = mu2;
    float wB0 = 0.f, wB1 = 0.f, wB2 = 0.f;
#define XSTEPA(O)                                                        \
    { float a0 = lanebc(pbase, 4 * (O), s0);                             \
      float a1 = lanebc(pbase, 4 * (O), s1);                             \
      float a2 = lanebc(pbase, 4 * (O), s2);                             \
      wA0 = fmaf(relem<3 * (O) + 0>(F0), a0, wA0);                       \
      wA1 = fmaf(relem<3 * (O) + 0>(F1), a0, wA1);                       \
      wA2 = fmaf(relem<3 * (O) + 0>(F2), a0, wA2);                       \
      wA0 = fmaf(relem<3 * (O) + 1>(F0), a1, wA0);                       \
      wA1 = fmaf(relem<3 * (O) + 1>(F1), a1, wA1);                       \
      wA2 = fmaf(relem<3 * (O) + 1>(F2), a1, wA2);                       \
      wA0 = fmaf(relem<3 * (O) + 2>(F0), a2, wA0);                       \
      wA1 = fmaf(relem<3 * (O) + 2>(F1), a2, wA1);                       \
      wA2 = fmaf(relem<3 * (O) + 2>(F2), a2, wA2); }
#define XSTEPB(O)                                                        \
    { float a0 = lanebc(pbase, 4 * (O), s0);                             \
      float a1 = lanebc(pbase, 4 * (O), s1);                             \
      float a2 = lanebc(pbase, 4 * (O), s2);                             \
      wB0 = fmaf(relem<3 * (O) + 0>(F0), a0, wB0);                       \
      wB1 = fmaf(relem<3 * (O) + 0>(F1), a0, wB1);                       \
      wB2 = fmaf(relem<3 * (O) + 0>(F2), a0, wB2);                       \
      wB0 = fmaf(relem<3 * (O) + 1>(F0), a1, wB0);                       \
      wB1 = fmaf(relem<3 * (O) + 1>(F1), a1, wB1);                       \
      wB2 = fmaf(relem<3 * (O) + 1>(F2), a1, wB2);                       \
      wB0 = fmaf(relem<3 * (O) + 2>(F0), a2, wB0);                       \
      wB1 = fmaf(relem<3 * (O) + 2>(F1), a2, wB1);                       \
      wB2 = fmaf(relem<3 * (O) + 2>(F2), a2, wB2); }
    XSTEPA(0) XSTEPA(1) XSTEPA(2) XSTEPA(3)
    XSTEPB(4) XSTEPB(5) XSTEPB(6) XSTEPB(7)
#undef XSTEPA
#undef XSTEPB
    float w0 = wA0 + wB0, w1 = wA1 + wB1, w2 = wA2 + wB2;
    float zp0 = fmaf(-2.0f, w0, s0);
    float zp1 = fmaf(-2.0f, w1, s1);
    float zp2 = fmaf(-2.0f, w2, s2);
    l0 = w0; l1 = w1; l2 = w2;
    if (t < 4) {                      // SOC cone t (rows 3t..3t+2, thread-local)
      float m = (zp2 > 0.0f) ? 1.0f : 0.0f;
      z0 = zp0 * m * cfr0; z1 = zp1 * m * cfr1; z2 = zp2 * m * cfr2;
    } else {                          // box rows 12..23
      z0 = fminf(fmaxf(zp0, -10.0f), 10.0f) * cfr0;
      z1 = fminf(fmaxf(zp1, -10.0f), 10.0f) * cfr1;
      z2 = fminf(fmaxf(zp2, -10.0f), 10.0f) * cfr2;
    }
  }

  // ---- outputs: lz, then x = (HtH)^-1 Ht (z - b) ----
  float* xout  = out;
  float* lzout = out + (size_t)Btot * 12;
  lzout[(size_t)env * 48 + r0w]          = l0;
  lzout[(size_t)env * 48 + r0w + 1]      = l1;
  lzout[(size_t)env * 48 + r0w + 2]      = l2;
  lzout[(size_t)env * 48 + 24 + r0w]     = z0;
  lzout[(size_t)env * 48 + 24 + r0w + 1] = z1;
  lzout[(size_t)env * 48 + 24 + r0w + 2] = z2;

  float bo0 = b[(size_t)env * 24 + r0w];
  float bo1 = b[(size_t)env * 24 + r0w + 1];
  float bo2 = b[(size_t)env * 24 + r0w + 2];
  WFENCE();
  auxB[r0w]     = z0 - bo0;
  auxB[r0w + 1] = z1 - bo1;
  auxB[r0w + 2] = z2 - bo2;
  WFENCE();

  float rv0 = 0.f, rv8 = 0.f;
#pragma unroll
  for (int k = 0; k < 24; ++k) rv0 = fmaf(myH[k * 12 + t], auxB[k], rv0);
  if (t < 4) {
#pragma unroll
    for (int k = 0; k < 24; ++k) rv8 = fmaf(myH[k * 12 + t + 8], auxB[k], rv8);
  }
  build_gram_row(myH, giB, t, false);
  if (t < 4) build_gram_row(myH, giB, t + 8, false);
  WFENCE();
  auxB[t] = rv0;
  if (t < 4) auxB[t + 8] = rv8;
  WFENCE();

  gj_all<0>(giB, t);
  {
    const float4* gr = (const float4*)(giB + t * 12);
    xout[(size_t)env * 12 + t] = dot12(gr[0], gr[1], gr[2], auxB);
    if (t < 4) {
      const float4* gr8 = (const float4*)(giB + (t + 8) * 12);
      xout[(size_t)env * 12 + t + 8] = dot12(gr8[0], gr8[1], gr8[2], auxB);
    }
  }
}

extern "C" void kernel_launch(void* const* d_in, const int* in_sizes, int n_in,
                              void* d_out, int out_size, void* d_ws, size_t ws_size,
                              hipStream_t stream) {
  const float* P  = (const float*)d_in[0];
  const float* q  = (const float*)d_in[1];
  const float* H  = (const float*)d_in[2];
  const float* b  = (const float*)d_in[3];
  const float* cf = (const float*)d_in[4];
  const int*   it = (const int*)d_in[5];
  float* out = (float*)d_out;
  const int B = in_sizes[1] / 12;       // q is [B,12]
  const int grid = B / EPB;             // 16384/8 = 2048 one-wave blocks
  pdhg_kernel<<<grid, BLOCK, 0, stream>>>(P, q, H, b, cf, it, out, B);
}

// Round 11
// 193.277 us; speedup vs baseline: 1.0095x; 1.0095x over previous
//
#include <hip/hip_runtime.h>

#define EPB 8           // envs per block
#define BLOCK 64        // ONE wave; env = 8 lanes (DPP-reachable group)
#define HS 292          // H LDS stride (288 + 4)
#define GS 148          // G/Ginv LDS stride (144 + 4)
#define SS 28           // b / aux stride (24 + 4)

#define WFENCE() __builtin_amdgcn_wave_barrier()   // compiler fence, 0 instr

#define DPP_XOR1 0xB1   // quad_perm [1,0,3,2]
#define DPP_XOR2 0x4E   // quad_perm [2,3,0,1]
#define DPP_HMIR 0x141  // row_half_mirror (i <-> 7-i within 8 lanes)

// acc += dot(f4, s4)
#define FMA4(acc, f, s)                                         \
  acc = fmaf((f).x, (s).x,                                      \
        fmaf((f).y, (s).y,                                      \
        fmaf((f).z, (s).z,                                      \
        fmaf((f).w, (s).w, (acc)))))

// acc4 += s * v4
#define VFMA(acc, s, v)                                         \
  { (acc).x = fmaf((s), (v).x, (acc).x);                        \
    (acc).y = fmaf((s), (v).y, (acc).y);                        \
    (acc).z = fmaf((s), (v).z, (acc).z);                        \
    (acc).w = fmaf((s), (v).w, (acc).w); }

struct Row6  { float4 a, b, c, d, e, f; };   // 24 floats, named chunks
struct Vec24 { float4 a, b, c, d, e, f; };

template<int CTRL>
__device__ __forceinline__ float dppv(float v) {
  return __int_as_float(__builtin_amdgcn_update_dpp(
      0, __float_as_int(v), CTRL, 0xF, 0xF, true));
}

// apply OP(chunk, comp) to all 24 components
#define APPLY24(OP)                                              \
  OP(a, x) OP(a, y) OP(a, z) OP(a, w)                            \
  OP(b, x) OP(b, y) OP(b, z) OP(b, w)                            \
  OP(c, x) OP(c, y) OP(c, z) OP(c, w)                            \
  OP(d, x) OP(d, y) OP(d, z) OP(d, w)                            \
  OP(e, x) OP(e, y) OP(e, z) OP(e, w)                            \
  OP(f, x) OP(f, y) OP(f, z) OP(f, w)

template<int K>
__device__ __forceinline__ float getel(const float4& a, const float4& b, const float4& c) {
  if constexpr (K == 0) return a.x; else if constexpr (K == 1) return a.y;
  else if constexpr (K == 2) return a.z; else if constexpr (K == 3) return a.w;
  else if constexpr (K == 4) return b.x; else if constexpr (K == 5) return b.y;
  else if constexpr (K == 6) return b.z; else if constexpr (K == 7) return b.w;
  else if constexpr (K == 8) return c.x; else if constexpr (K == 9) return c.y;
  else if constexpr (K == 10) return c.z; else return c.w;
}
template<int K>
__device__ __forceinline__ void setel(float4& a, float4& b, float4& c, float v) {
  if constexpr (K == 0) a.x = v; else if constexpr (K == 1) a.y = v;
  else if constexpr (K == 2) a.z = v; else if constexpr (K == 3) a.w = v;
  else if constexpr (K == 4) b.x = v; else if constexpr (K == 5) b.y = v;
  else if constexpr (K == 6) b.z = v; else if constexpr (K == 7) b.w = v;
  else if constexpr (K == 8) c.x = v; else if constexpr (K == 9) c.y = v;
  else if constexpr (K == 10) c.z = v; else c.w = v;
}

// In-place Gauss-Jordan inversion step in LDS (SPD, no pivoting). Wave-internal.
template<int K>
__device__ __forceinline__ void gj_step(float* A, int t) {
  if (t == K || t + 8 == K) {
    float4* r = (float4*)(A + K * 12);
    float4 a = r[0], b = r[1], c = r[2];
    float ip = 1.0f / getel<K>(a, b, c);
    setel<K>(a, b, c, 1.0f);
    a.x *= ip; a.y *= ip; a.z *= ip; a.w *= ip;
    b.x *= ip; b.y *= ip; b.z *= ip; b.w *= ip;
    c.x *= ip; c.y *= ip; c.z *= ip; c.w *= ip;
    r[0] = a; r[1] = b; r[2] = c;
  }
  WFENCE();
  const float4* pr = (const float4*)(A + K * 12);
  float4 p0 = pr[0], p1 = pr[1], p2 = pr[2];
  {
    float4* rr = (float4*)(A + t * 12);
    float4 a = rr[0], b = rr[1], c = rr[2];
    float f = getel<K>(a, b, c);
    if (t == K) f = 0.0f; else setel<K>(a, b, c, 0.0f);
    a.x = fmaf(-f, p0.x, a.x); a.y = fmaf(-f, p0.y, a.y);
    a.z = fmaf(-f, p0.z, a.z); a.w = fmaf(-f, p0.w, a.w);
    b.x = fmaf(-f, p1.x, b.x); b.y = fmaf(-f, p1.y, b.y);
    b.z = fmaf(-f, p1.z, b.z); b.w = fmaf(-f, p1.w, b.w);
    c.x = fmaf(-f, p2.x, c.x); c.y = fmaf(-f, p2.y, c.y);
    c.z = fmaf(-f, p2.z, c.z); c.w = fmaf(-f, p2.w, c.w);
    rr[0] = a; rr[1] = b; rr[2] = c;
  }
  if (t < 4) {
    const int i = t + 8;
    float4* rr = (float4*)(A + i * 12);
    float4 a = rr[0], b = rr[1], c = rr[2];
    float f = getel<K>(a, b, c);
    if (i == K) f = 0.0f; else setel<K>(a, b, c, 0.0f);
    a.x = fmaf(-f, p0.x, a.x); a.y = fmaf(-f, p0.y, a.y);
    a.z = fmaf(-f, p0.z, a.z); a.w = fmaf(-f, p0.w, a.w);
    b.x = fmaf(-f, p1.x, b.x); b.y = fmaf(-f, p1.y, b.y);
    b.z = fmaf(-f, p1.z, b.z); b.w = fmaf(-f, p1.w, b.w);
    c.x = fmaf(-f, p2.x, c.x); c.y = fmaf(-f, p2.y, c.y);
    c.z = fmaf(-f, p2.z, c.z); c.w = fmaf(-f, p2.w, c.w);
    rr[0] = a; rr[1] = b; rr[2] = c;
  }
  WFENCE();
}
template<int K>
__device__ __forceinline__ void gj_all(float* A, int t) {
  gj_step<K>(A, t);
  if constexpr (K < 11) gj_all<K + 1>(A, t);
}

__device__ __forceinline__ float dot12(float4 a0, float4 a1, float4 a2,
                                       const float* p) {
  const float4* p4 = (const float4*)p;
  float4 b0 = p4[0], b1 = p4[1], b2 = p4[2];
  float acc = 0.f;
  FMA4(acc, a0, b0); FMA4(acc, a1, b1); FMA4(acc, a2, b2);
  return acc;
}

__device__ __forceinline__ void build_gram_row(const float* myH, float* gi,
                                               int i, bool addP) {
  float4 a0 = {0,0,0,0}, a1 = {0,0,0,0}, a2 = {0,0,0,0};
#pragma unroll
  for (int k = 0; k < 24; ++k) {
    float coef = myH[k * 12 + i];
    const float4* hk = (const float4*)(myH + k * 12);
    float4 h0 = hk[0], h1 = hk[1], h2 = hk[2];
    VFMA(a0, coef, h0); VFMA(a1, coef, h1); VFMA(a2, coef, h2);
  }
  float4* g = (float4*)(gi + i * 12);
  if (addP) {
    float4 q0 = g[0], q1 = g[1], q2 = g[2];
    a0.x += q0.x; a0.y += q0.y; a0.z += q0.z; a0.w += q0.w;
    a1.x += q1.x; a1.y += q1.y; a1.z += q1.z; a1.w += q1.w;
    a2.x += q2.x; a2.y += q2.y; a2.z += q2.z; a2.w += q2.w;
  }
  g[0] = a0; g[1] = a1; g[2] = a2;
}

// Fm row r = e_r - (H[r,:]*Ginv)*H^T. Fm is SYMMETRIC (Ginv SPD), so this is
// also column r — used as the column in the DPP loop.
__device__ __forceinline__ Row6 build_row(const float* myH, const float* gi, int r) {
  const float4* hr4 = (const float4*)(myH + r * 12);
  float4 h0 = hr4[0], h1 = hr4[1], h2 = hr4[2];
  float4 gA = {0,0,0,0}, gB = {0,0,0,0}, gC = {0,0,0,0};
#define ACC_G(c, coef)                                          \
  { const float4* g4 = (const float4*)(gi + (c) * 12);          \
    float4 r0 = g4[0], r1 = g4[1], r2 = g4[2];                  \
    VFMA(gA, coef, r0); VFMA(gB, coef, r1); VFMA(gC, coef, r2); }
  ACC_G(0, h0.x) ACC_G(1, h0.y) ACC_G(2,  h0.z) ACC_G(3,  h0.w)
  ACC_G(4, h1.x) ACC_G(5, h1.y) ACC_G(6,  h1.z) ACC_G(7,  h1.w)
  ACC_G(8, h2.x) ACC_G(9, h2.y) ACC_G(10, h2.z) ACC_G(11, h2.w)
#undef ACC_G
  Row6 R;
#define FEL(j) ((((j) == r) ? 1.0f : 0.0f) - dot12(gA, gB, gC, myH + (j) * 12))
  R.a = make_float4(FEL(0),  FEL(1),  FEL(2),  FEL(3));
  R.b = make_float4(FEL(4),  FEL(5),  FEL(6),  FEL(7));
  R.c = make_float4(FEL(8),  FEL(9),  FEL(10), FEL(11));
  R.d = make_float4(FEL(12), FEL(13), FEL(14), FEL(15));
  R.e = make_float4(FEL(16), FEL(17), FEL(18), FEL(19));
  R.f = make_float4(FEL(20), FEL(21), FEL(22), FEL(23));
#undef FEL
  return R;
}

__global__ __launch_bounds__(BLOCK)
void pdhg_kernel(const float* __restrict__ P, const float* __restrict__ q,
                 const float* __restrict__ H, const float* __restrict__ b,
                 const float* __restrict__ cf, const int* __restrict__ itp,
                 float* __restrict__ out, int Btot) {
  __shared__ __align__(16) float sH[EPB * HS];
  __shared__ __align__(16) float sGi[EPB * GS];   // P -> G -> Ginv -> HtH -> inv
  __shared__ __align__(16) float sB[EPB * SS];    // b (setup only)
  __shared__ __align__(16) float sAux[EPB * SS];  // q|y, later z-b

  const int tid = threadIdx.x;                    // 0..63, one wave
  const int e   = tid >> 3;
  const int t   = tid & 7;
  const int env = blockIdx.x * EPB + e;
  const int niter = itp[0];
  const int r0w = 3 * t;

  // ---- per-wave float4 staging: H, P, q, b ----
  {
    const float4* gH = (const float4*)(H + (size_t)blockIdx.x * EPB * 288);
#pragma unroll
    for (int rep = 0; rep < 9; ++rep) {           // 8*72 = 576 float4
      int i = tid + rep * 64;
      int ee = i / 72, off = i - ee * 72;
      *(float4*)&sH[ee * HS + off * 4] = gH[i];
    }
    const float4* gP = (const float4*)(P + (size_t)blockIdx.x * EPB * 144);
#pragma unroll
    for (int rep = 0; rep < 4; ++rep) {           // 8*36 = 288 float4
      int i = tid + rep * 64;
      int ee = i / 36, off = i - ee * 36;
      *(float4*)&sGi[ee * GS + off * 4] = gP[i];
    }
    { int i = tid + 256; if (tid < 32) {
        int ee = i / 36, off = i - ee * 36;
        *(float4*)&sGi[ee * GS + off * 4] = gP[i]; } }
    const float4* gq = (const float4*)(q + (size_t)blockIdx.x * EPB * 12);
    if (tid < EPB * 3) {
      int ee = tid / 3, off = tid - ee * 3;
      *(float4*)&sAux[ee * SS + off * 4] = gq[tid];
    }
    const float4* gb = (const float4*)(b + (size_t)blockIdx.x * EPB * 24);
    if (tid < EPB * 6) {
      int ee = tid / 6, off = tid - ee * 6;
      *(float4*)&sB[ee * SS + off * 4] = gb[tid];
    }
  }
  WFENCE();

  const float* myH = &sH[e * HS];
  float* giB = &sGi[e * GS];
  float* auxB = &sAux[e * SS];
  const float* bB = &sB[e * SS];

  // ---- G = P + HtH; invert in place (wave-internal, no barriers) ----
  build_gram_row(myH, giB, t, true);
  if (t < 4) build_gram_row(myH, giB, t + 8, true);
  WFENCE();
  gj_all<0>(giB, t);

  // ---- y = Ginv * q ----
  {
    const float4* gr = (const float4*)(giB + t * 12);
    auxB[12 + t] = dot12(gr[0], gr[1], gr[2], auxB);
    if (t < 4) {
      const float4* gr8 = (const float4*)(giB + (t + 8) * 12);
      auxB[12 + t + 8] = dot12(gr8[0], gr8[1], gr8[2], auxB);
    }
  }
  WFENCE();

  // ---- Fm cols 3t..3t+2 (= rows, symmetric), mu = H*y - Fm*b ----
  Row6 Fc0 = build_row(myH, giB, r0w + 0);
  Row6 Fc1 = build_row(myH, giB, r0w + 1);
  Row6 Fc2 = build_row(myH, giB, r0w + 2);
  float mu0, mu1, mu2;
  {
    const float4* h0 = (const float4*)(myH + (r0w + 0) * 12);
    const float4* h1 = (const float4*)(myH + (r0w + 1) * 12);
    const float4* h2 = (const float4*)(myH + (r0w + 2) * 12);
    const float* y = auxB + 12;
    float u0 = dot12(h0[0], h0[1], h0[2], y);
    float u1 = dot12(h1[0], h1[1], h1[2], y);
    float u2 = dot12(h2[0], h2[1], h2[2], y);
    const float4* bv = (const float4*)bB;
    float d0 = 0.f, d1 = 0.f, d2 = 0.f;
    float4 v;
    v = bv[0]; FMA4(d0, Fc0.a, v); FMA4(d1, Fc1.a, v); FMA4(d2, Fc2.a, v);
    v = bv[1]; FMA4(d0, Fc0.b, v); FMA4(d1, Fc1.b, v); FMA4(d2, Fc2.b, v);
    v = bv[2]; FMA4(d0, Fc0.c, v); FMA4(d1, Fc1.c, v); FMA4(d2, Fc2.c, v);
    v = bv[3]; FMA4(d0, Fc0.d, v); FMA4(d1, Fc1.d, v); FMA4(d2, Fc2.d, v);
    v = bv[4]; FMA4(d0, Fc0.e, v); FMA4(d1, Fc1.e, v); FMA4(d2, Fc2.e, v);
    v = bv[5]; FMA4(d0, Fc0.f, v); FMA4(d1, Fc1.f, v); FMA4(d2, Fc2.f, v);
    mu0 = u0 - d0;
    mu1 = u1 - d1;
    mu2 = u2 - d2;
  }
  float cfr0 = cf[(size_t)env * 24 + r0w];
  float cfr1 = cf[(size_t)env * 24 + r0w + 1];
  float cfr2 = cf[(size_t)env * 24 + r0w + 2];

  // selection predicates for the extraction tree (hoisted)
  const bool tb0 = (t & 1) != 0;
  const bool tb1 = (t & 2) != 0;
  const bool tb2 = (t & 4) != 0;

  // ---- iterations: column decomposition + DPP all-reduce. ZERO DS ops. ----
  float l0 = 0.f, l1 = 0.f, l2 = 0.f, z0 = 0.f, z1 = 0.f, z2 = 0.f;
  for (int it = 0; it < niter; ++it) {
    float s0 = l0 + z0, s1 = l1 + z1, s2 = l2 + z2;
    Vec24 Y;
    // partials: Y[j] = F[j][3t]*s0 + F[j][3t+1]*s1 + F[j][3t+2]*s2
#define YFMA(C, X) Y.C.X = fmaf(Fc2.C.X, s2, fmaf(Fc1.C.X, s1, Fc0.C.X * s0));
    APPLY24(YFMA)
#undef YFMA
    // 8-lane all-reduce within the env: xor1, xor2 (quad sums), half-mirror
#define YR1(C, X) Y.C.X += dppv<DPP_XOR1>(Y.C.X);
    APPLY24(YR1)
#undef YR1
#define YR2(C, X) Y.C.X += dppv<DPP_XOR2>(Y.C.X);
    APPLY24(YR2)
#undef YR2
#define YR3(C, X) Y.C.X += dppv<DPP_HMIR>(Y.C.X);
    APPLY24(YR3)
#undef YR3
    // extract own rows 3t..3t+2 via cndmask tree (verified lane->index table:
    // w0: ax,aw,bz,cy,dx,dw,ez,fy | w1: ay,bx,bw,cz,dy,ex,ew,fz |
    // w2: az,by,cx,cw,dz,ey,fx,fw  for t=0..7)
    float w0, w1, w2;
    {
      float a_, b_, c_, d_, e_, f_;
      a_ = tb0 ? Y.a.w : Y.a.x;  b_ = tb0 ? Y.c.y : Y.b.z;
      c_ = tb0 ? Y.d.w : Y.d.x;  d_ = tb0 ? Y.f.y : Y.e.z;
      e_ = tb1 ? b_ : a_;        f_ = tb1 ? d_ : c_;
      w0 = (tb2 ? f_ : e_) + mu0;
      a_ = tb0 ? Y.b.x : Y.a.y;  b_ = tb0 ? Y.c.z : Y.b.w;
      c_ = tb0 ? Y.e.x : Y.d.y;  d_ = tb0 ? Y.f.z : Y.e.w;
      e_ = tb1 ? b_ : a_;        f_ = tb1 ? d_ : c_;
      w1 = (tb2 ? f_ : e_) + mu1;
      a_ = tb0 ? Y.b.y : Y.a.z;  b_ = tb0 ? Y.c.w : Y.c.x;
      c_ = tb0 ? Y.e.y : Y.d.z;  d_ = tb0 ? Y.f.w : Y.f.x;
      e_ = tb1 ? b_ : a_;        f_ = tb1 ? d_ : c_;
      w2 = (tb2 ? f_ : e_) + mu2;
    }
    float zp0 = fmaf(-2.0f, w0, s0);
    float zp1 = fmaf(-2.0f, w1, s1);
    float zp2 = fmaf(-2.0f, w2, s2);
    l0 = w0; l1 = w1; l2 = w2;
    if (t < 4) {                      // SOC cone t (rows 3t..3t+2, thread-local)
      float m = (zp2 > 0.0f) ? 1.0f : 0.0f;
      z0 = zp0 * m * cfr0; z1 = zp1 * m * cfr1; z2 = zp2 * m * cfr2;
    } else {                          // box rows 12..23
      z0 = fminf(fmaxf(zp0, -10.0f), 10.0f) * cfr0;
      z1 = fminf(fmaxf(zp1, -10.0f), 10.0f) * cfr1;
      z2 = fminf(fmaxf(zp2, -10.0f), 10.0f) * cfr2;
    }
  }

  // ---- outputs: lz, then x = (HtH)^-1 Ht (z - b) ----
  float* xout  = out;
  float* lzout = out + (size_t)Btot * 12;
  lzout[(size_t)env * 48 + r0w]          = l0;
  lzout[(size_t)env * 48 + r0w + 1]      = l1;
  lzout[(size_t)env * 48 + r0w + 2]      = l2;
  lzout[(size_t)env * 48 + 24 + r0w]     = z0;
  lzout[(size_t)env * 48 + 24 + r0w + 1] = z1;
  lzout[(size_t)env * 48 + 24 + r0w + 2] = z2;

  float bo0 = b[(size_t)env * 24 + r0w];
  float bo1 = b[(size_t)env * 24 + r0w + 1];
  float bo2 = b[(size_t)env * 24 + r0w + 2];
  WFENCE();
  auxB[r0w]     = z0 - bo0;
  auxB[r0w + 1] = z1 - bo1;
  auxB[r0w + 2] = z2 - bo2;
  WFENCE();

  float rv0 = 0.f, rv8 = 0.f;
#pragma unroll
  for (int k = 0; k < 24; ++k) rv0 = fmaf(myH[k * 12 + t], auxB[k], rv0);
  if (t < 4) {
#pragma unroll
    for (int k = 0; k < 24; ++k) rv8 = fmaf(myH[k * 12 + t + 8], auxB[k], rv8);
  }
  build_gram_row(myH, giB, t, false);
  if (t < 4) build_gram_row(myH, giB, t + 8, false);
  WFENCE();
  auxB[t] = rv0;
  if (t < 4) auxB[t + 8] = rv8;
  WFENCE();

  gj_all<0>(giB, t);
  {
    const float4* gr = (const float4*)(giB + t * 12);
    xout[(size_t)env * 12 + t] = dot12(gr[0], gr[1], gr[2], auxB);
    if (t < 4) {
      const float4* gr8 = (const float4*)(giB + (t + 8) * 12);
      xout[(size_t)env * 12 + t + 8] = dot12(gr8[0], gr8[1], gr8[2], auxB);
    }
  }
}

extern "C" void kernel_launch(void* const* d_in, const int* in_sizes, int n_in,
                              void* d_out, int out_size, void* d_ws, size_t ws_size,
                              hipStream_t stream) {
  const float* P  = (const float*)d_in[0];
  const float* q  = (const float*)d_in[1];
  const float* H  = (const float*)d_in[2];
  const float* b  = (const float*)d_in[3];
  const float* cf = (const float*)d_in[4];
  const int*   it = (const int*)d_in[5];
  float* out = (float*)d_out;
  const int B = in_sizes[1] / 12;       // q is [B,12]
  const int grid = B / EPB;             // 16384/8 = 2048 one-wave blocks
  pdhg_kernel<<<grid, BLOCK, 0, stream>>>(P, q, H, b, cf, it, out, B);
}

// Round 12
// 186.331 us; speedup vs baseline: 1.0472x; 1.0373x over previous
//
#include <hip/hip_runtime.h>

#define EPB 32          // envs per block (8 per wave)
#define BLOCK 256       // 4 independent waves; env = 8 lanes, wave-internal
#define HS 292          // H LDS stride (288 + 4)
#define GS 148          // G/Ginv LDS stride (144 + 4)
#define SS 28           // b / aux stride (24 + 4)

#define WFENCE() __builtin_amdgcn_wave_barrier()   // compiler fence, 0 instr

#define DPP_XOR1 0xB1   // quad_perm [1,0,3,2]
#define DPP_XOR2 0x4E   // quad_perm [2,3,0,1]
#define DPP_HMIR 0x141  // row_half_mirror (i <-> 7-i within 8 lanes)

// acc += dot(f4, s4)
#define FMA4(acc, f, s)                                         \
  acc = fmaf((f).x, (s).x,                                      \
        fmaf((f).y, (s).y,                                      \
        fmaf((f).z, (s).z,                                      \
        fmaf((f).w, (s).w, (acc)))))

// acc4 += s * v4
#define VFMA(acc, s, v)                                         \
  { (acc).x = fmaf((s), (v).x, (acc).x);                        \
    (acc).y = fmaf((s), (v).y, (acc).y);                        \
    (acc).z = fmaf((s), (v).z, (acc).z);                        \
    (acc).w = fmaf((s), (v).w, (acc).w); }

struct Row6  { float4 a, b, c, d, e, f; };   // 24 floats, named chunks
struct Vec24 { float4 a, b, c, d, e, f; };

template<int CTRL>
__device__ __forceinline__ float dppv(float v) {
  return __int_as_float(__builtin_amdgcn_update_dpp(
      0, __float_as_int(v), CTRL, 0xF, 0xF, true));
}

// apply OP(chunk, comp) to all 24 components
#define APPLY24(OP)                                              \
  OP(a, x) OP(a, y) OP(a, z) OP(a, w)                            \
  OP(b, x) OP(b, y) OP(b, z) OP(b, w)                            \
  OP(c, x) OP(c, y) OP(c, z) OP(c, w)                            \
  OP(d, x) OP(d, y) OP(d, z) OP(d, w)                            \
  OP(e, x) OP(e, y) OP(e, z) OP(e, w)                            \
  OP(f, x) OP(f, y) OP(f, z) OP(f, w)

template<int K>
__device__ __forceinline__ float getel(const float4& a, const float4& b, const float4& c) {
  if constexpr (K == 0) return a.x; else if constexpr (K == 1) return a.y;
  else if constexpr (K == 2) return a.z; else if constexpr (K == 3) return a.w;
  else if constexpr (K == 4) return b.x; else if constexpr (K == 5) return b.y;
  else if constexpr (K == 6) return b.z; else if constexpr (K == 7) return b.w;
  else if constexpr (K == 8) return c.x; else if constexpr (K == 9) return c.y;
  else if constexpr (K == 10) return c.z; else return c.w;
}
template<int K>
__device__ __forceinline__ void setel(float4& a, float4& b, float4& c, float v) {
  if constexpr (K == 0) a.x = v; else if constexpr (K == 1) a.y = v;
  else if constexpr (K == 2) a.z = v; else if constexpr (K == 3) a.w = v;
  else if constexpr (K == 4) b.x = v; else if constexpr (K == 5) b.y = v;
  else if constexpr (K == 6) b.z = v; else if constexpr (K == 7) b.w = v;
  else if constexpr (K == 8) c.x = v; else if constexpr (K == 9) c.y = v;
  else if constexpr (K == 10) c.z = v; else c.w = v;
}

// In-place Gauss-Jordan inversion step in LDS (SPD, no pivoting). Wave-internal.
template<int K>
__device__ __forceinline__ void gj_step(float* A, int t) {
  if (t == K || t + 8 == K) {
    float4* r = (float4*)(A + K * 12);
    float4 a = r[0], b = r[1], c = r[2];
    float ip = 1.0f / getel<K>(a, b, c);
    setel<K>(a, b, c, 1.0f);
    a.x *= ip; a.y *= ip; a.z *= ip; a.w *= ip;
    b.x *= ip; b.y *= ip; b.z *= ip; b.w *= ip;
    c.x *= ip; c.y *= ip; c.z *= ip; c.w *= ip;
    r[0] = a; r[1] = b; r[2] = c;
  }
  WFENCE();
  const float4* pr = (const float4*)(A + K * 12);
  float4 p0 = pr[0], p1 = pr[1], p2 = pr[2];
  {
    float4* rr = (float4*)(A + t * 12);
    float4 a = rr[0], b = rr[1], c = rr[2];
    float f = getel<K>(a, b, c);
    if (t == K) f = 0.0f; else setel<K>(a, b, c, 0.0f);
    a.x = fmaf(-f, p0.x, a.x); a.y = fmaf(-f, p0.y, a.y);
    a.z = fmaf(-f, p0.z, a.z); a.w = fmaf(-f, p0.w, a.w);
    b.x = fmaf(-f, p1.x, b.x); b.y = fmaf(-f, p1.y, b.y);
    b.z = fmaf(-f, p1.z, b.z); b.w = fmaf(-f, p1.w, b.w);
    c.x = fmaf(-f, p2.x, c.x); c.y = fmaf(-f, p2.y, c.y);
    c.z = fmaf(-f, p2.z, c.z); c.w = fmaf(-f, p2.w, c.w);
    rr[0] = a; rr[1] = b; rr[2] = c;
  }
  if (t < 4) {
    const int i = t + 8;
    float4* rr = (float4*)(A + i * 12);
    float4 a = rr[0], b = rr[1], c = rr[2];
    float f = getel<K>(a, b, c);
    if (i == K) f = 0.0f; else setel<K>(a, b, c, 0.0f);
    a.x = fmaf(-f, p0.x, a.x); a.y = fmaf(-f, p0.y, a.y);
    a.z = fmaf(-f, p0.z, a.z); a.w = fmaf(-f, p0.w, a.w);
    b.x = fmaf(-f, p1.x, b.x); b.y = fmaf(-f, p1.y, b.y);
    b.z = fmaf(-f, p1.z, b.z); b.w = fmaf(-f, p1.w, b.w);
    c.x = fmaf(-f, p2.x, c.x); c.y = fmaf(-f, p2.y, c.y);
    c.z = fmaf(-f, p2.z, c.z); c.w = fmaf(-f, p2.w, c.w);
    rr[0] = a; rr[1] = b; rr[2] = c;
  }
  WFENCE();
}
template<int K>
__device__ __forceinline__ void gj_all(float* A, int t) {
  gj_step<K>(A, t);
  if constexpr (K < 11) gj_all<K + 1>(A, t);
}

__device__ __forceinline__ float dot12(float4 a0, float4 a1, float4 a2,
                                       const float* p) {
  const float4* p4 = (const float4*)p;
  float4 b0 = p4[0], b1 = p4[1], b2 = p4[2];
  float acc = 0.f;
  FMA4(acc, a0, b0); FMA4(acc, a1, b1); FMA4(acc, a2, b2);
  return acc;
}

__device__ __forceinline__ void build_gram_row(const float* myH, float* gi,
                                               int i, bool addP) {
  float4 a0 = {0,0,0,0}, a1 = {0,0,0,0}, a2 = {0,0,0,0};
#pragma unroll
  for (int k = 0; k < 24; ++k) {
    float coef = myH[k * 12 + i];
    const float4* hk = (const float4*)(myH + k * 12);
    float4 h0 = hk[0], h1 = hk[1], h2 = hk[2];
    VFMA(a0, coef, h0); VFMA(a1, coef, h1); VFMA(a2, coef, h2);
  }
  float4* g = (float4*)(gi + i * 12);
  if (addP) {
    float4 q0 = g[0], q1 = g[1], q2 = g[2];
    a0.x += q0.x; a0.y += q0.y; a0.z += q0.z; a0.w += q0.w;
    a1.x += q1.x; a1.y += q1.y; a1.z += q1.z; a1.w += q1.w;
    a2.x += q2.x; a2.y += q2.y; a2.z += q2.z; a2.w += q2.w;
  }
  g[0] = a0; g[1] = a1; g[2] = a2;
}

// Fm row r = e_r - (H[r,:]*Ginv)*H^T. Fm is SYMMETRIC (Ginv SPD), so this is
// also column r — used as the column in the DPP loop.
__device__ __forceinline__ Row6 build_row(const float* myH, const float* gi, int r) {
  const float4* hr4 = (const float4*)(myH + r * 12);
  float4 h0 = hr4[0], h1 = hr4[1], h2 = hr4[2];
  float4 gA = {0,0,0,0}, gB = {0,0,0,0}, gC = {0,0,0,0};
#define ACC_G(c, coef)                                          \
  { const float4* g4 = (const float4*)(gi + (c) * 12);          \
    float4 r0 = g4[0], r1 = g4[1], r2 = g4[2];                  \
    VFMA(gA, coef, r0); VFMA(gB, coef, r1); VFMA(gC, coef, r2); }
  ACC_G(0, h0.x) ACC_G(1, h0.y) ACC_G(2,  h0.z) ACC_G(3,  h0.w)
  ACC_G(4, h1.x) ACC_G(5, h1.y) ACC_G(6,  h1.z) ACC_G(7,  h1.w)
  ACC_G(8, h2.x) ACC_G(9, h2.y) ACC_G(10, h2.z) ACC_G(11, h2.w)
#undef ACC_G
  Row6 R;
#define FEL(j) ((((j) == r) ? 1.0f : 0.0f) - dot12(gA, gB, gC, myH + (j) * 12))
  R.a = make_float4(FEL(0),  FEL(1),  FEL(2),  FEL(3));
  R.b = make_float4(FEL(4),  FEL(5),  FEL(6),  FEL(7));
  R.c = make_float4(FEL(8),  FEL(9),  FEL(10), FEL(11));
  R.d = make_float4(FEL(12), FEL(13), FEL(14), FEL(15));
  R.e = make_float4(FEL(16), FEL(17), FEL(18), FEL(19));
  R.f = make_float4(FEL(20), FEL(21), FEL(22), FEL(23));
#undef FEL
  return R;
}

__global__ __attribute__((amdgpu_flat_work_group_size(BLOCK, BLOCK),
                          amdgpu_waves_per_eu(1, 4)))
void pdhg_kernel(const float* __restrict__ P, const float* __restrict__ q,
                 const float* __restrict__ H, const float* __restrict__ b,
                 const float* __restrict__ cf, const int* __restrict__ itp,
                 float* __restrict__ out, int Btot) {
  __shared__ __align__(16) float sH[EPB * HS];    // 37376 B
  __shared__ __align__(16) float sGi[EPB * GS];   // 18944 B
  __shared__ __align__(16) float sB[EPB * SS];    //  3584 B
  __shared__ __align__(16) float sAux[EPB * SS];  //  3584 B  (total 63488)

  const int tid  = threadIdx.x;
  const int wq   = tid >> 6;          // wave 0..3 — fully independent
  const int lane = tid & 63;
  const int e    = wq * 8 + (lane >> 3);          // env local 0..31
  const int t    = lane & 7;
  const int env  = blockIdx.x * EPB + e;
  const int envW0 = blockIdx.x * EPB + wq * 8;    // wave's first env
  const int niter = itp[0];
  const int r0w = 3 * t;

  // ---- PER-WAVE float4 staging of this wave's 8 envs: H, P, q, b ----
  {
    const float4* gH = (const float4*)(H + (size_t)envW0 * 288);
#pragma unroll
    for (int rep = 0; rep < 9; ++rep) {           // 8*72 = 576 float4
      int i = lane + rep * 64;
      int ee = i / 72, off = i - ee * 72;
      *(float4*)&sH[(wq * 8 + ee) * HS + off * 4] = gH[i];
    }
    const float4* gP = (const float4*)(P + (size_t)envW0 * 144);
#pragma unroll
    for (int rep = 0; rep < 4; ++rep) {           // 8*36 = 288 float4
      int i = lane + rep * 64;
      int ee = i / 36, off = i - ee * 36;
      *(float4*)&sGi[(wq * 8 + ee) * GS + off * 4] = gP[i];
    }
    { int i = lane + 256; if (lane < 32) {
        int ee = i / 36, off = i - ee * 36;
        *(float4*)&sGi[(wq * 8 + ee) * GS + off * 4] = gP[i]; } }
    const float4* gq = (const float4*)(q + (size_t)envW0 * 12);
    if (lane < 24) {                              // 8*3 float4
      int ee = lane / 3, off = lane - ee * 3;
      *(float4*)&sAux[(wq * 8 + ee) * SS + off * 4] = gq[lane];
    }
    const float4* gb = (const float4*)(b + (size_t)envW0 * 24);
    if (lane < 48) {                              // 8*6 float4
      int ee = lane / 6, off = lane - ee * 6;
      *(float4*)&sB[(wq * 8 + ee) * SS + off * 4] = gb[lane];
    }
  }
  WFENCE();   // producers and consumers are the same wave — no barrier needed

  const float* myH = &sH[e * HS];
  float* giB = &sGi[e * GS];
  float* auxB = &sAux[e * SS];
  const float* bB = &sB[e * SS];

  // ---- G = P + HtH; invert in place (wave-internal, no barriers) ----
  build_gram_row(myH, giB, t, true);
  if (t < 4) build_gram_row(myH, giB, t + 8, true);
  WFENCE();
  gj_all<0>(giB, t);

  // ---- y = Ginv * q ----
  {
    const float4* gr = (const float4*)(giB + t * 12);
    auxB[12 + t] = dot12(gr[0], gr[1], gr[2], auxB);
    if (t < 4) {
      const float4* gr8 = (const float4*)(giB + (t + 8) * 12);
      auxB[12 + t + 8] = dot12(gr8[0], gr8[1], gr8[2], auxB);
    }
  }
  WFENCE();

  // ---- Fm cols 3t..3t+2 (= rows, symmetric), mu = H*y - Fm*b ----
  Row6 Fc0 = build_row(myH, giB, r0w + 0);
  Row6 Fc1 = build_row(myH, giB, r0w + 1);
  Row6 Fc2 = build_row(myH, giB, r0w + 2);
  float mu0, mu1, mu2;
  {
    const float4* h0 = (const float4*)(myH + (r0w + 0) * 12);
    const float4* h1 = (const float4*)(myH + (r0w + 1) * 12);
    const float4* h2 = (const float4*)(myH + (r0w + 2) * 12);
    const float* y = auxB + 12;
    float u0 = dot12(h0[0], h0[1], h0[2], y);
    float u1 = dot12(h1[0], h1[1], h1[2], y);
    float u2 = dot12(h2[0], h2[1], h2[2], y);
    const float4* bv = (const float4*)bB;
    float d0 = 0.f, d1 = 0.f, d2 = 0.f;
    float4 v;
    v = bv[0]; FMA4(d0, Fc0.a, v); FMA4(d1, Fc1.a, v); FMA4(d2, Fc2.a, v);
    v = bv[1]; FMA4(d0, Fc0.b, v); FMA4(d1, Fc1.b, v); FMA4(d2, Fc2.b, v);
    v = bv[2]; FMA4(d0, Fc0.c, v); FMA4(d1, Fc1.c, v); FMA4(d2, Fc2.c, v);
    v = bv[3]; FMA4(d0, Fc0.d, v); FMA4(d1, Fc1.d, v); FMA4(d2, Fc2.d, v);
    v = bv[4]; FMA4(d0, Fc0.e, v); FMA4(d1, Fc1.e, v); FMA4(d2, Fc2.e, v);
    v = bv[5]; FMA4(d0, Fc0.f, v); FMA4(d1, Fc1.f, v); FMA4(d2, Fc2.f, v);
    mu0 = u0 - d0;
    mu1 = u1 - d1;
    mu2 = u2 - d2;
  }
  float cfr0 = cf[(size_t)env * 24 + r0w];
  float cfr1 = cf[(size_t)env * 24 + r0w + 1];
  float cfr2 = cf[(size_t)env * 24 + r0w + 2];

  // selection predicates for the extraction tree (hoisted)
  const bool tb0 = (t & 1) != 0;
  const bool tb1 = (t & 2) != 0;
  const bool tb2 = (t & 4) != 0;

  // ---- iterations: column decomposition + DPP all-reduce. ZERO DS ops. ----
  float l0 = 0.f, l1 = 0.f, l2 = 0.f, z0 = 0.f, z1 = 0.f, z2 = 0.f;
  for (int it = 0; it < niter; ++it) {
    float s0 = l0 + z0, s1 = l1 + z1, s2 = l2 + z2;
    Vec24 Y;
#define YFMA(C, X) Y.C.X = fmaf(Fc2.C.X, s2, fmaf(Fc1.C.X, s1, Fc0.C.X * s0));
    APPLY24(YFMA)
#undef YFMA
#define YR1(C, X) Y.C.X += dppv<DPP_XOR1>(Y.C.X);
    APPLY24(YR1)
#undef YR1
#define YR2(C, X) Y.C.X += dppv<DPP_XOR2>(Y.C.X);
    APPLY24(YR2)
#undef YR2
#define YR3(C, X) Y.C.X += dppv<DPP_HMIR>(Y.C.X);
    APPLY24(YR3)
#undef YR3
    // extract own rows 3t..3t+2 (verified lane->index table)
    float w0, w1, w2;
    {
      float a_, b_, c_, d_, e_, f_;
      a_ = tb0 ? Y.a.w : Y.a.x;  b_ = tb0 ? Y.c.y : Y.b.z;
      c_ = tb0 ? Y.d.w : Y.d.x;  d_ = tb0 ? Y.f.y : Y.e.z;
      e_ = tb1 ? b_ : a_;        f_ = tb1 ? d_ : c_;
      w0 = (tb2 ? f_ : e_) + mu0;
      a_ = tb0 ? Y.b.x : Y.a.y;  b_ = tb0 ? Y.c.z : Y.b.w;
      c_ = tb0 ? Y.e.x : Y.d.y;  d_ = tb0 ? Y.f.z : Y.e.w;
      e_ = tb1 ? b_ : a_;        f_ = tb1 ? d_ : c_;
      w1 = (tb2 ? f_ : e_) + mu1;
      a_ = tb0 ? Y.b.y : Y.a.z;  b_ = tb0 ? Y.c.w : Y.c.x;
      c_ = tb0 ? Y.e.y : Y.d.z;  d_ = tb0 ? Y.f.w : Y.f.x;
      e_ = tb1 ? b_ : a_;        f_ = tb1 ? d_ : c_;
      w2 = (tb2 ? f_ : e_) + mu2;
    }
    float zp0 = fmaf(-2.0f, w0, s0);
    float zp1 = fmaf(-2.0f, w1, s1);
    float zp2 = fmaf(-2.0f, w2, s2);
    l0 = w0; l1 = w1; l2 = w2;
    if (t < 4) {                      // SOC cone t (rows 3t..3t+2, thread-local)
      float m = (zp2 > 0.0f) ? 1.0f : 0.0f;
      z0 = zp0 * m * cfr0; z1 = zp1 * m * cfr1; z2 = zp2 * m * cfr2;
    } else {                          // box rows 12..23
      z0 = fminf(fmaxf(zp0, -10.0f), 10.0f) * cfr0;
      z1 = fminf(fmaxf(zp1, -10.0f), 10.0f) * cfr1;
      z2 = fminf(fmaxf(zp2, -10.0f), 10.0f) * cfr2;
    }
  }

  // ---- outputs: lz, then x = (HtH)^-1 Ht (z - b) ----
  float* xout  = out;
  float* lzout = out + (size_t)Btot * 12;
  lzout[(size_t)env * 48 + r0w]          = l0;
  lzout[(size_t)env * 48 + r0w + 1]      = l1;
  lzout[(size_t)env * 48 + r0w + 2]      = l2;
  lzout[(size_t)env * 48 + 24 + r0w]     = z0;
  lzout[(size_t)env * 48 + 24 + r0w + 1] = z1;
  lzout[(size_t)env * 48 + 24 + r0w + 2] = z2;

  float bo0 = b[(size_t)env * 24 + r0w];
  float bo1 = b[(size_t)env * 24 + r0w + 1];
  float bo2 = b[(size_t)env * 24 + r0w + 2];
  WFENCE();
  auxB[r0w]     = z0 - bo0;
  auxB[r0w + 1] = z1 - bo1;
  auxB[r0w + 2] = z2 - bo2;
  WFENCE();

  float rv0 = 0.f, rv8 = 0.f;
#pragma unroll
  for (int k = 0; k < 24; ++k) rv0 = fmaf(myH[k * 12 + t], auxB[k], rv0);
  if (t < 4) {
#pragma unroll
    for (int k = 0; k < 24; ++k) rv8 = fmaf(myH[k * 12 + t + 8], auxB[k], rv8);
  }
  build_gram_row(myH, giB, t, false);
  if (t < 4) build_gram_row(myH, giB, t + 8, false);
  WFENCE();
  auxB[t] = rv0;
  if (t < 4) auxB[t + 8] = rv8;
  WFENCE();

  gj_all<0>(giB, t);
  {
    const float4* gr = (const float4*)(giB + t * 12);
    xout[(size_t)env * 12 + t] = dot12(gr[0], gr[1], gr[2], auxB);
    if (t < 4) {
      const float4* gr8 = (const float4*)(giB + (t + 8) * 12);
      xout[(size_t)env * 12 + t + 8] = dot12(gr8[0], gr8[1], gr8[2], auxB);
    }
  }
}

extern "C" void kernel_launch(void* const* d_in, const int* in_sizes, int n_in,
                              void* d_out, int out_size, void* d_ws, size_t ws_size,
                              hipStream_t stream) {
  const float* P  = (const float*)d_in[0];
  const float* q  = (const float*)d_in[1];
  const float* H  = (const float*)d_in[2];
  const float* b  = (const float*)d_in[3];
  const float* cf = (const float*)d_in[4];
  const int*   it = (const int*)d_in[5];
  float* out = (float*)d_out;
  const int B = in_sizes[1] / 12;       // q is [B,12]
  const int grid = B / EPB;             // 16384/32 = 512 blocks, 2/CU resident
  pdhg_kernel<<<grid, BLOCK, 0, stream>>>(P, q, H, b, cf, it, out, B);
}

// Round 13
// 152.985 us; speedup vs baseline: 1.2754x; 1.2180x over previous
//
#include <hip/hip_runtime.h>

#define EPB 32          // envs per block (8 per wave)
#define BLOCK 256       // 4 independent waves; env = 8 lanes, wave-internal
#define HS 292          // H LDS stride (288 + 4)
#define GS 148          // G/Ginv LDS stride (144 + 4)
#define SS 28           // b / aux stride (24 + 4)

#define WFENCE() __builtin_amdgcn_wave_barrier()   // compiler fence, 0 instr

#define DPP_XOR1 0xB1   // quad_perm [1,0,3,2]  : lane ^= 1
#define DPP_XOR2 0x4E   // quad_perm [2,3,0,1]  : lane ^= 2
#define DPP_HMIR 0x141  // row_half_mirror      : lane ^= 7 (within 8)

// gather slot-group g (0..7) holds the s-triple of lane (t ^ GMAP[g]):
// slots built as [own, xor1, xor2(own,xor1), hmir(first 12)]
__device__ __constant__ const int GMAP[8] = {0, 1, 2, 3, 7, 6, 5, 4};

// acc += dot(f4, s4)
#define FMA4(acc, f, s)                                         \
  acc = fmaf((f).x, (s).x,                                      \
        fmaf((f).y, (s).y,                                      \
        fmaf((f).z, (s).z,                                      \
        fmaf((f).w, (s).w, (acc)))))

// acc4 += s * v4
#define VFMA(acc, s, v)                                         \
  { (acc).x = fmaf((s), (v).x, (acc).x);                        \
    (acc).y = fmaf((s), (v).y, (acc).y);                        \
    (acc).z = fmaf((s), (v).z, (acc).z);                        \
    (acc).w = fmaf((s), (v).w, (acc).w); }

struct Row6 { float4 a, b, c, d, e, f; };   // 24 floats, named chunks

template<int CTRL>
__device__ __forceinline__ float dppv(float v) {
  return __int_as_float(__builtin_amdgcn_update_dpp(
      0, __float_as_int(v), CTRL, 0xF, 0xF, true));
}

template<int K>
__device__ __forceinline__ float getel(const float4& a, const float4& b, const float4& c) {
  if constexpr (K == 0) return a.x; else if constexpr (K == 1) return a.y;
  else if constexpr (K == 2) return a.z; else if constexpr (K == 3) return a.w;
  else if constexpr (K == 4) return b.x; else if constexpr (K == 5) return b.y;
  else if constexpr (K == 6) return b.z; else if constexpr (K == 7) return b.w;
  else if constexpr (K == 8) return c.x; else if constexpr (K == 9) return c.y;
  else if constexpr (K == 10) return c.z; else return c.w;
}
template<int K>
__device__ __forceinline__ void setel(float4& a, float4& b, float4& c, float v) {
  if constexpr (K == 0) a.x = v; else if constexpr (K == 1) a.y = v;
  else if constexpr (K == 2) a.z = v; else if constexpr (K == 3) a.w = v;
  else if constexpr (K == 4) b.x = v; else if constexpr (K == 5) b.y = v;
  else if constexpr (K == 6) b.z = v; else if constexpr (K == 7) b.w = v;
  else if constexpr (K == 8) c.x = v; else if constexpr (K == 9) c.y = v;
  else if constexpr (K == 10) c.z = v; else c.w = v;
}

// In-place Gauss-Jordan inversion step in LDS (SPD, no pivoting). Wave-internal.
template<int K>
__device__ __forceinline__ void gj_step(float* A, int t) {
  if (t == K || t + 8 == K) {
    float4* r = (float4*)(A + K * 12);
    float4 a = r[0], b = r[1], c = r[2];
    float ip = 1.0f / getel<K>(a, b, c);
    setel<K>(a, b, c, 1.0f);
    a.x *= ip; a.y *= ip; a.z *= ip; a.w *= ip;
    b.x *= ip; b.y *= ip; b.z *= ip; b.w *= ip;
    c.x *= ip; c.y *= ip; c.z *= ip; c.w *= ip;
    r[0] = a; r[1] = b; r[2] = c;
  }
  WFENCE();
  const float4* pr = (const float4*)(A + K * 12);
  float4 p0 = pr[0], p1 = pr[1], p2 = pr[2];
  {
    float4* rr = (float4*)(A + t * 12);
    float4 a = rr[0], b = rr[1], c = rr[2];
    float f = getel<K>(a, b, c);
    if (t == K) f = 0.0f; else setel<K>(a, b, c, 0.0f);
    a.x = fmaf(-f, p0.x, a.x); a.y = fmaf(-f, p0.y, a.y);
    a.z = fmaf(-f, p0.z, a.z); a.w = fmaf(-f, p0.w, a.w);
    b.x = fmaf(-f, p1.x, b.x); b.y = fmaf(-f, p1.y, b.y);
    b.z = fmaf(-f, p1.z, b.z); b.w = fmaf(-f, p1.w, b.w);
    c.x = fmaf(-f, p2.x, c.x); c.y = fmaf(-f, p2.y, c.y);
    c.z = fmaf(-f, p2.z, c.z); c.w = fmaf(-f, p2.w, c.w);
    rr[0] = a; rr[1] = b; rr[2] = c;
  }
  if (t < 4) {
    const int i = t + 8;
    float4* rr = (float4*)(A + i * 12);
    float4 a = rr[0], b = rr[1], c = rr[2];
    float f = getel<K>(a, b, c);
    if (i == K) f = 0.0f; else setel<K>(a, b, c, 0.0f);
    a.x = fmaf(-f, p0.x, a.x); a.y = fmaf(-f, p0.y, a.y);
    a.z = fmaf(-f, p0.z, a.z); a.w = fmaf(-f, p0.w, a.w);
    b.x = fmaf(-f, p1.x, b.x); b.y = fmaf(-f, p1.y, b.y);
    b.z = fmaf(-f, p1.z, b.z); b.w = fmaf(-f, p1.w, b.w);
    c.x = fmaf(-f, p2.x, c.x); c.y = fmaf(-f, p2.y, c.y);
    c.z = fmaf(-f, p2.z, c.z); c.w = fmaf(-f, p2.w, c.w);
    rr[0] = a; rr[1] = b; rr[2] = c;
  }
  WFENCE();
}
template<int K>
__device__ __forceinline__ void gj_all(float* A, int t) {
  gj_step<K>(A, t);
  if constexpr (K < 11) gj_all<K + 1>(A, t);
}

__device__ __forceinline__ float dot12(float4 a0, float4 a1, float4 a2,
                                       const float* p) {
  const float4* p4 = (const float4*)p;
  float4 b0 = p4[0], b1 = p4[1], b2 = p4[2];
  float acc = 0.f;
  FMA4(acc, a0, b0); FMA4(acc, a1, b1); FMA4(acc, a2, b2);
  return acc;
}

__device__ __forceinline__ void build_gram_row(const float* myH, float* gi,
                                               int i, bool addP) {
  float4 a0 = {0,0,0,0}, a1 = {0,0,0,0}, a2 = {0,0,0,0};
#pragma unroll
  for (int k = 0; k < 24; ++k) {
    float coef = myH[k * 12 + i];
    const float4* hk = (const float4*)(myH + k * 12);
    float4 h0 = hk[0], h1 = hk[1], h2 = hk[2];
    VFMA(a0, coef, h0); VFMA(a1, coef, h1); VFMA(a2, coef, h2);
  }
  float4* g = (float4*)(gi + i * 12);
  if (addP) {
    float4 q0 = g[0], q1 = g[1], q2 = g[2];
    a0.x += q0.x; a0.y += q0.y; a0.z += q0.z; a0.w += q0.w;
    a1.x += q1.x; a1.y += q1.y; a1.z += q1.z; a1.w += q1.w;
    a2.x += q2.x; a2.y += q2.y; a2.z += q2.z; a2.w += q2.w;
  }
  g[0] = a0; g[1] = a1; g[2] = a2;
}

// element S (0..23) of lane t's COLUMN-PERMUTED Fm row r:
// slot (g,k): column j = 3*(t ^ GMAP[g]) + k  (matches the DPP gather order)
template<int S>
__device__ __forceinline__ float pel(const float* myH, int r, int t,
                                     float4 gA, float4 gB, float4 gC) {
  constexpr int g = S / 3, k = S % 3;
  const int j = 3 * (t ^ GMAP[g]) + k;
  float v = dot12(gA, gB, gC, myH + j * 12);
  return ((j == r) ? 1.0f : 0.0f) - v;
}

// Permuted Fm row r = e_r - (H[r,:]*Ginv)*H^T with columns in gather order.
__device__ __forceinline__ Row6 build_row_perm(const float* myH, const float* gi,
                                               int r, int t) {
  const float4* hr4 = (const float4*)(myH + r * 12);
  float4 h0 = hr4[0], h1 = hr4[1], h2 = hr4[2];
  float4 gA = {0,0,0,0}, gB = {0,0,0,0}, gC = {0,0,0,0};
#define ACC_G(c, coef)                                          \
  { const float4* g4 = (const float4*)(gi + (c) * 12);          \
    float4 r0 = g4[0], r1 = g4[1], r2 = g4[2];                  \
    VFMA(gA, coef, r0); VFMA(gB, coef, r1); VFMA(gC, coef, r2); }
  ACC_G(0, h0.x) ACC_G(1, h0.y) ACC_G(2,  h0.z) ACC_G(3,  h0.w)
  ACC_G(4, h1.x) ACC_G(5, h1.y) ACC_G(6,  h1.z) ACC_G(7,  h1.w)
  ACC_G(8, h2.x) ACC_G(9, h2.y) ACC_G(10, h2.z) ACC_G(11, h2.w)
#undef ACC_G
  Row6 R;
  R.a = make_float4(pel<0>(myH,r,t,gA,gB,gC),  pel<1>(myH,r,t,gA,gB,gC),
                    pel<2>(myH,r,t,gA,gB,gC),  pel<3>(myH,r,t,gA,gB,gC));
  R.b = make_float4(pel<4>(myH,r,t,gA,gB,gC),  pel<5>(myH,r,t,gA,gB,gC),
                    pel<6>(myH,r,t,gA,gB,gC),  pel<7>(myH,r,t,gA,gB,gC));
  R.c = make_float4(pel<8>(myH,r,t,gA,gB,gC),  pel<9>(myH,r,t,gA,gB,gC),
                    pel<10>(myH,r,t,gA,gB,gC), pel<11>(myH,r,t,gA,gB,gC));
  R.d = make_float4(pel<12>(myH,r,t,gA,gB,gC), pel<13>(myH,r,t,gA,gB,gC),
                    pel<14>(myH,r,t,gA,gB,gC), pel<15>(myH,r,t,gA,gB,gC));
  R.e = make_float4(pel<16>(myH,r,t,gA,gB,gC), pel<17>(myH,r,t,gA,gB,gC),
                    pel<18>(myH,r,t,gA,gB,gC), pel<19>(myH,r,t,gA,gB,gC));
  R.f = make_float4(pel<20>(myH,r,t,gA,gB,gC), pel<21>(myH,r,t,gA,gB,gC),
                    pel<22>(myH,r,t,gA,gB,gC), pel<23>(myH,r,t,gA,gB,gC));
  return R;
}

// b element in gather-permuted slot S
template<int S>
__device__ __forceinline__ float bgat(const float* bB, int t) {
  constexpr int g = S / 3, k = S % 3;
  return bB[3 * (t ^ GMAP[g]) + k];
}

__global__ __attribute__((amdgpu_flat_work_group_size(BLOCK, BLOCK),
                          amdgpu_waves_per_eu(1, 4)))
void pdhg_kernel(const float* __restrict__ P, const float* __restrict__ q,
                 const float* __restrict__ H, const float* __restrict__ b,
                 const float* __restrict__ cf, const int* __restrict__ itp,
                 float* __restrict__ out, int Btot) {
  __shared__ __align__(16) float sH[EPB * HS];
  __shared__ __align__(16) float sGi[EPB * GS];
  __shared__ __align__(16) float sB[EPB * SS];
  __shared__ __align__(16) float sAux[EPB * SS];

  const int tid  = threadIdx.x;
  const int wq   = tid >> 6;          // wave 0..3 — fully independent
  const int lane = tid & 63;
  const int e    = wq * 8 + (lane >> 3);
  const int t    = lane & 7;
  const int env  = blockIdx.x * EPB + e;
  const int envW0 = blockIdx.x * EPB + wq * 8;
  const int niter = itp[0];
  const int r0w = 3 * t;

  // ---- PER-WAVE float4 staging of this wave's 8 envs: H, P, q, b ----
  {
    const float4* gH = (const float4*)(H + (size_t)envW0 * 288);
#pragma unroll
    for (int rep = 0; rep < 9; ++rep) {
      int i = lane + rep * 64;
      int ee = i / 72, off = i - ee * 72;
      *(float4*)&sH[(wq * 8 + ee) * HS + off * 4] = gH[i];
    }
    const float4* gP = (const float4*)(P + (size_t)envW0 * 144);
#pragma unroll
    for (int rep = 0; rep < 4; ++rep) {
      int i = lane + rep * 64;
      int ee = i / 36, off = i - ee * 36;
      *(float4*)&sGi[(wq * 8 + ee) * GS + off * 4] = gP[i];
    }
    { int i = lane + 256; if (lane < 32) {
        int ee = i / 36, off = i - ee * 36;
        *(float4*)&sGi[(wq * 8 + ee) * GS + off * 4] = gP[i]; } }
    const float4* gq = (const float4*)(q + (size_t)envW0 * 12);
    if (lane < 24) {
      int ee = lane / 3, off = lane - ee * 3;
      *(float4*)&sAux[(wq * 8 + ee) * SS + off * 4] = gq[lane];
    }
    const float4* gb = (const float4*)(b + (size_t)envW0 * 24);
    if (lane < 48) {
      int ee = lane / 6, off = lane - ee * 6;
      *(float4*)&sB[(wq * 8 + ee) * SS + off * 4] = gb[lane];
    }
  }
  WFENCE();

  const float* myH = &sH[e * HS];
  float* giB = &sGi[e * GS];
  float* auxB = &sAux[e * SS];
  const float* bB = &sB[e * SS];

  // ---- G = P + HtH; invert in place (wave-internal, no barriers) ----
  build_gram_row(myH, giB, t, true);
  if (t < 4) build_gram_row(myH, giB, t + 8, true);
  WFENCE();
  gj_all<0>(giB, t);

  // ---- y = Ginv * q ----
  {
    const float4* gr = (const float4*)(giB + t * 12);
    auxB[12 + t] = dot12(gr[0], gr[1], gr[2], auxB);
    if (t < 4) {
      const float4* gr8 = (const float4*)(giB + (t + 8) * 12);
      auxB[12 + t + 8] = dot12(gr8[0], gr8[1], gr8[2], auxB);
    }
  }
  WFENCE();

  // ---- column-PERMUTED Fm rows; mu = H*y - Fm*b (b gathered permuted) ----
  Row6 Pm0 = build_row_perm(myH, giB, r0w + 0, t);
  Row6 Pm1 = build_row_perm(myH, giB, r0w + 1, t);
  Row6 Pm2 = build_row_perm(myH, giB, r0w + 2, t);
  float mu0, mu1, mu2;
  {
    const float4* h0 = (const float4*)(myH + (r0w + 0) * 12);
    const float4* h1 = (const float4*)(myH + (r0w + 1) * 12);
    const float4* h2 = (const float4*)(myH + (r0w + 2) * 12);
    const float* y = auxB + 12;
    float u0 = dot12(h0[0], h0[1], h0[2], y);
    float u1 = dot12(h1[0], h1[1], h1[2], y);
    float u2 = dot12(h2[0], h2[1], h2[2], y);
    float4 bg0 = make_float4(bgat<0>(bB,t),  bgat<1>(bB,t),  bgat<2>(bB,t),  bgat<3>(bB,t));
    float4 bg1 = make_float4(bgat<4>(bB,t),  bgat<5>(bB,t),  bgat<6>(bB,t),  bgat<7>(bB,t));
    float4 bg2 = make_float4(bgat<8>(bB,t),  bgat<9>(bB,t),  bgat<10>(bB,t), bgat<11>(bB,t));
    float4 bg3 = make_float4(bgat<12>(bB,t), bgat<13>(bB,t), bgat<14>(bB,t), bgat<15>(bB,t));
    float4 bg4 = make_float4(bgat<16>(bB,t), bgat<17>(bB,t), bgat<18>(bB,t), bgat<19>(bB,t));
    float4 bg5 = make_float4(bgat<20>(bB,t), bgat<21>(bB,t), bgat<22>(bB,t), bgat<23>(bB,t));
    float d0 = 0.f, d1 = 0.f, d2 = 0.f;
    FMA4(d0, Pm0.a, bg0); FMA4(d1, Pm1.a, bg0); FMA4(d2, Pm2.a, bg0);
    FMA4(d0, Pm0.b, bg1); FMA4(d1, Pm1.b, bg1); FMA4(d2, Pm2.b, bg1);
    FMA4(d0, Pm0.c, bg2); FMA4(d1, Pm1.c, bg2); FMA4(d2, Pm2.c, bg2);
    FMA4(d0, Pm0.d, bg3); FMA4(d1, Pm1.d, bg3); FMA4(d2, Pm2.d, bg3);
    FMA4(d0, Pm0.e, bg4); FMA4(d1, Pm1.e, bg4); FMA4(d2, Pm2.e, bg4);
    FMA4(d0, Pm0.f, bg5); FMA4(d1, Pm1.f, bg5); FMA4(d2, Pm2.f, bg5);
    mu0 = u0 - d0;
    mu1 = u1 - d1;
    mu2 = u2 - d2;
  }
  float cfr0 = cf[(size_t)env * 24 + r0w];
  float cfr1 = cf[(size_t)env * 24 + r0w + 1];
  float cfr2 = cf[(size_t)env * 24 + r0w + 2];

  // ---- iterations: 21-op DPP all-gather of s + 72 row-FMAs. ZERO DS. ----
  float l0 = 0.f, l1 = 0.f, l2 = 0.f, z0 = 0.f, z1 = 0.f, z2 = 0.f;
  for (int it = 0; it < niter; ++it) {
    float s0 = l0 + z0, s1 = l1 + z1, s2 = l2 + z2;
    // all-gather: slots [t, t^1, t^2, t^3, t^7, t^6, t^5, t^4] (= GMAP order)
    float g3  = dppv<DPP_XOR1>(s0), g4  = dppv<DPP_XOR1>(s1), g5  = dppv<DPP_XOR1>(s2);
    float g6  = dppv<DPP_XOR2>(s0), g7  = dppv<DPP_XOR2>(s1), g8  = dppv<DPP_XOR2>(s2);
    float g9  = dppv<DPP_XOR2>(g3), g10 = dppv<DPP_XOR2>(g4), g11 = dppv<DPP_XOR2>(g5);
    float g12 = dppv<DPP_HMIR>(s0), g13 = dppv<DPP_HMIR>(s1), g14 = dppv<DPP_HMIR>(s2);
    float g15 = dppv<DPP_HMIR>(g3), g16 = dppv<DPP_HMIR>(g4), g17 = dppv<DPP_HMIR>(g5);
    float g18 = dppv<DPP_HMIR>(g6), g19 = dppv<DPP_HMIR>(g7), g20 = dppv<DPP_HMIR>(g8);
    float g21 = dppv<DPP_HMIR>(g9), g22 = dppv<DPP_HMIR>(g10), g23 = dppv<DPP_HMIR>(g11);
    float4 v0 = make_float4(s0,  s1,  s2,  g3);
    float4 v1 = make_float4(g4,  g5,  g6,  g7);
    float4 v2 = make_float4(g8,  g9,  g10, g11);
    float4 v3 = make_float4(g12, g13, g14, g15);
    float4 v4 = make_float4(g16, g17, g18, g19);
    float4 v5 = make_float4(g20, g21, g22, g23);
    // two chains per row
    float a0 = mu0, a1 = mu1, a2 = mu2, b0 = 0.f, b1 = 0.f, b2 = 0.f;
    FMA4(a0, Pm0.a, v0); FMA4(a1, Pm1.a, v0); FMA4(a2, Pm2.a, v0);
    FMA4(a0, Pm0.b, v1); FMA4(a1, Pm1.b, v1); FMA4(a2, Pm2.b, v1);
    FMA4(a0, Pm0.c, v2); FMA4(a1, Pm1.c, v2); FMA4(a2, Pm2.c, v2);
    FMA4(b0, Pm0.d, v3); FMA4(b1, Pm1.d, v3); FMA4(b2, Pm2.d, v3);
    FMA4(b0, Pm0.e, v4); FMA4(b1, Pm1.e, v4); FMA4(b2, Pm2.e, v4);
    FMA4(b0, Pm0.f, v5); FMA4(b1, Pm1.f, v5); FMA4(b2, Pm2.f, v5);
    float w0 = a0 + b0, w1 = a1 + b1, w2 = a2 + b2;
    float zp0 = fmaf(-2.0f, w0, s0);
    float zp1 = fmaf(-2.0f, w1, s1);
    float zp2 = fmaf(-2.0f, w2, s2);
    l0 = w0; l1 = w1; l2 = w2;
    if (t < 4) {                      // SOC cone t (rows 3t..3t+2, thread-local)
      float m = (zp2 > 0.0f) ? 1.0f : 0.0f;
      z0 = zp0 * m * cfr0; z1 = zp1 * m * cfr1; z2 = zp2 * m * cfr2;
    } else {                          // box rows 12..23
      z0 = fminf(fmaxf(zp0, -10.0f), 10.0f) * cfr0;
      z1 = fminf(fmaxf(zp1, -10.0f), 10.0f) * cfr1;
      z2 = fminf(fmaxf(zp2, -10.0f), 10.0f) * cfr2;
    }
  }

  // ---- outputs: lz, then x = (HtH)^-1 Ht (z - b) ----
  float* xout  = out;
  float* lzout = out + (size_t)Btot * 12;
  lzout[(size_t)env * 48 + r0w]          = l0;
  lzout[(size_t)env * 48 + r0w + 1]      = l1;
  lzout[(size_t)env * 48 + r0w + 2]      = l2;
  lzout[(size_t)env * 48 + 24 + r0w]     = z0;
  lzout[(size_t)env * 48 + 24 + r0w + 1] = z1;
  lzout[(size_t)env * 48 + 24 + r0w + 2] = z2;

  float bo0 = b[(size_t)env * 24 + r0w];
  float bo1 = b[(size_t)env * 24 + r0w + 1];
  float bo2 = b[(size_t)env * 24 + r0w + 2];
  WFENCE();
  auxB[r0w]     = z0 - bo0;
  auxB[r0w + 1] = z1 - bo1;
  auxB[r0w + 2] = z2 - bo2;
  WFENCE();

  float rv0 = 0.f, rv8 = 0.f;
#pragma unroll
  for (int k = 0; k < 24; ++k) rv0 = fmaf(myH[k * 12 + t], auxB[k], rv0);
  if (t < 4) {
#pragma unroll
    for (int k = 0; k < 24; ++k) rv8 = fmaf(myH[k * 12 + t + 8], auxB[k], rv8);
  }
  build_gram_row(myH, giB, t, false);
  if (t < 4) build_gram_row(myH, giB, t + 8, false);
  WFENCE();
  auxB[t] = rv0;
  if (t < 4) auxB[t + 8] = rv8;
  WFENCE();

  gj_all<0>(giB, t);
  {
    const float4* gr = (const float4*)(giB + t * 12);
    xout[(size_t)env * 12 + t] = dot12(gr[0], gr[1], gr[2], auxB);
    if (t < 4) {
      const float4* gr8 = (const float4*)(giB + (t + 8) * 12);
      xout[(size_t)env * 12 + t + 8] = dot12(gr8[0], gr8[1], gr8[2], auxB);
    }
  }
}

extern "C" void kernel_launch(void* const* d_in, const int* in_sizes, int n_in,
                              void* d_out, int out_size, void* d_ws, size_t ws_size,
                              hipStream_t stream) {
  const float* P  = (const float*)d_in[0];
  const float* q  = (const float*)d_in[1];
  const float* H  = (const float*)d_in[2];
  const float* b  = (const float*)d_in[3];
  const float* cf = (const float*)d_in[4];
  const int*   it = (const int*)d_in[5];
  float* out = (float*)d_out;
  const int B = in_sizes[1] / 12;       // q is [B,12]
  const int grid = B / EPB;             // 16384/32 = 512 blocks
  pdhg_kernel<<<grid, BLOCK, 0, stream>>>(P, q, H, b, cf, it, out, B);
}